// Round 6
// baseline (476.501 us; speedup 1.0000x reference)
//
#include <hip/hip_runtime.h>

// STN round 6: conv1 via packed fp32 (v_pk_fma_f32, 2 FMA/inst).
// K1: localization -> theta. Conv1 threads (o,u,q) compute out-row pair
//     (2u,2u+1) as float2 accumulators (pool partners -> pooling in-register,
//     no shuffles). Image in LDS as two phase-interleaved row-pair layouts
//     (s2e even pairs, s2o odd pairs) so every kh reads aligned b128 pairs.
//     Weights duplicated {w,w} in LDS -> plain pk_fma, no op_sel.
// K2: bilinear sampling (unchanged, ~17 us, write-bound).

typedef float v2f __attribute__((ext_vector_type(2)));

#define PK_FMA(acc, a, w) \
    asm("v_pk_fma_f32 %0, %1, %2, %0" : "+v"(acc) : "v"(a), "v"(w))

__launch_bounds__(256, 4)
__global__ void stn_loc_kernel(
    const float* __restrict__ x,
    const float* __restrict__ w1, const float* __restrict__ b1,
    const float* __restrict__ w2, const float* __restrict__ b2,
    const float* __restrict__ fc1w, const float* __restrict__ fc1b,
    const float* __restrict__ fc2w, const float* __restrict__ fc2b,
    float* __restrict__ theta_ws)
{
    // image row-pair layouts, float2-interleaved, row stride 30 pairs (240 B)
    __shared__ __align__(16) float s2e_f[3 * 14 * 30 * 2];  // pairs (2h,2h+1)
    __shared__ __align__(16) float s2o_f[3 * 13 * 30 * 2];  // pairs (2h+1,2h+2)
    __shared__ __align__(16) float s_w1d[8 * 170 * 2];      // {w,w} pairs, o-stride 170
    __shared__ __align__(16) float s_h1[8 * 11 * 12];       // pooled1, rows padded to 12
    __shared__ float s_h2[90];
    __shared__ float s_fch[32];

    const int t = threadIdx.x;
    const int n = blockIdx.x;
    const float* img = x + (size_t)n * 2352;

    // ---- Stage A: image HWC -> phase-paired LDS; weights -> duplicated pairs
    for (int p = t; p < 784; p += 256) {
        const int h = p / 28, w = p - 28 * h;
        #pragma unroll
        for (int c = 0; c < 3; ++c) {
            const float v = img[3 * p + c];
            // even-phase: pair (2a, 2a+1), a = h>>1, parity h&1
            s2e_f[((c * 14 + (h >> 1)) * 30 + w) * 2 + (h & 1)] = v;
            // odd-phase: rows 1..26 -> pair (2a+1, 2a+2), a = (h-1)>>1
            if (h >= 1 && h <= 26) {
                s2o_f[((c * 13 + ((h - 1) >> 1)) * 30 + w) * 2 + ((h - 1) & 1)] = v;
            }
        }
    }
    for (int i = t; i < 1176; i += 256) {
        const int o = i / 147, r0 = i - 147 * o;
        const int c = r0 / 49, r1 = r0 - 49 * c;
        const int kh = r1 / 7, kw = r1 - 7 * kh;
        const float v = w1[i];
        const int dst = (o * 170 + (c * 7 + kh) * 8 + kw) * 2;
        s_w1d[dst] = v;
        s_w1d[dst + 1] = v;
    }
    __syncthreads();

    // ---- Stage B: conv1 (3->8, 7x7) + 2x2 maxpool + relu -> s_h1 [8][11][12]
    // t = u*16 + o*2 + q: u = out-row-pair 0..10, o = channel, q = col half.
    if (t < 176) {
        const int u = t >> 4;
        const int o = (t >> 1) & 7;
        const int q = t & 1;
        const int cb0 = q * 12;   // col base (float2 units)

        v2f acc2[12];
        const float bias = b1[o];
        #pragma unroll
        for (int j = 0; j < 12; ++j) acc2[j] = (v2f){bias, bias};

        for (int c = 0; c < 3; ++c) {
            #pragma unroll
            for (int kh = 0; kh < 7; ++kh) {
                const int a = u + (kh >> 1);
                const float* rowbase = (kh & 1)
                    ? &s2o_f[((c * 13 + a) * 30 + cb0) * 2]
                    : &s2e_f[((c * 14 + a) * 30 + cb0) * 2];
                v2f P[18];
                const float4* src = (const float4*)rowbase;
                #pragma unroll
                for (int r = 0; r < 9; ++r) {
                    float4 v = src[r];
                    P[2 * r]     = (v2f){v.x, v.y};
                    P[2 * r + 1] = (v2f){v.z, v.w};
                }
                v2f wd[7];
                const float* wbase = &s_w1d[(o * 170 + (c * 7 + kh) * 8) * 2];
                {
                    const float4* ws4 = (const float4*)wbase;
                    float4 v;
                    v = ws4[0]; wd[0] = (v2f){v.x, v.y}; wd[1] = (v2f){v.z, v.w};
                    v = ws4[1]; wd[2] = (v2f){v.x, v.y}; wd[3] = (v2f){v.z, v.w};
                    v = ws4[2]; wd[4] = (v2f){v.x, v.y}; wd[5] = (v2f){v.z, v.w};
                    wd[6] = *(const v2f*)&wbase[12];
                }
                #pragma unroll
                for (int kw = 0; kw < 7; ++kw) {
                    #pragma unroll
                    for (int j = 0; j < 12; ++j) {
                        PK_FMA(acc2[j], P[j + kw], wd[kw]);
                    }
                }
            }
        }
        // pooling fully in-register: rows (2u,2u+1) are .x/.y; col pairs (2m,2m+1)
        const int mmax = q ? 5 : 6;
        float* hrow = &s_h1[(o * 11 + u) * 12 + q * 6];
        #pragma unroll
        for (int m = 0; m < 6; ++m) {
            if (m < mmax) {
                float v = fmaxf(fmaxf(acc2[2 * m][0], acc2[2 * m][1]),
                                fmaxf(acc2[2 * m + 1][0], acc2[2 * m + 1][1]));
                hrow[m] = fmaxf(v, 0.0f);
            }
        }
    }
    __syncthreads();

    // ---- Stage D: conv2 (8->10, 5x5) + 2x2 maxpool + relu -> s_h2[90]
    // 60 threads (round-4 proven form, low conflicts); weights from global.
    if (t < 60) {
        const int o = t / 6, i = t - 6 * (t / 6);
        float acc2[6];
        const float bias = b2[o];
        #pragma unroll
        for (int j = 0; j < 6; ++j) acc2[j] = bias;
        for (int c = 0; c < 8; ++c) {
            #pragma unroll
            for (int kh = 0; kh < 5; ++kh) {
                const float* hrow = &s_h1[(c * 11 + i + kh) * 12];
                float im2[12];
                #pragma unroll
                for (int q = 0; q < 3; ++q) {
                    float4 v = ((const float4*)hrow)[q];
                    im2[4 * q + 0] = v.x; im2[4 * q + 1] = v.y;
                    im2[4 * q + 2] = v.z; im2[4 * q + 3] = v.w;
                }
                const float* wr = &w2[(o * 8 + c) * 25 + kh * 5];
                float wv[5];
                #pragma unroll
                for (int qq = 0; qq < 5; ++qq) wv[qq] = wr[qq];
                #pragma unroll
                for (int kw = 0; kw < 5; ++kw) {
                    #pragma unroll
                    for (int j = 0; j < 6; ++j)
                        acc2[j] += im2[j + kw] * wv[kw];
                }
            }
        }
        float hp[3];
        #pragma unroll
        for (int q = 0; q < 3; ++q) hp[q] = fmaxf(acc2[2 * q], acc2[2 * q + 1]);
        #pragma unroll
        for (int q = 0; q < 3; ++q) {
            float v = __shfl_xor(hp[q], 1);   // partner i^1 = lane^1
            hp[q] = fmaxf(hp[q], v);
        }
        if ((i & 1) == 0) {
            #pragma unroll
            for (int q = 0; q < 3; ++q)
                s_h2[o * 9 + (i >> 1) * 3 + q] = fmaxf(hp[q], 0.0f);
        }
    }
    __syncthreads();

    // ---- Stage F: fc1 (90->32) + relu; 256 threads = 32 outputs x 8 lanes
    {
        const int of = t >> 3, l = t & 7;
        float acc = 0.0f;
        const float* wr = &fc1w[of * 90];
        #pragma unroll
        for (int m = 0; m < 12; ++m) {
            int j = l + 8 * m;
            if (j < 90) acc += s_h2[j] * wr[j];
        }
        acc += __shfl_xor(acc, 1);
        acc += __shfl_xor(acc, 2);
        acc += __shfl_xor(acc, 4);
        if (l == 0) s_fch[of] = fmaxf(acc + fc1b[of], 0.0f);
    }
    __syncthreads();

    // ---- Stage G: fc2 (32->6); 48 threads = 6 outputs x 8 lanes -> theta
    if (t < 48) {
        const int of = t >> 3, l = t & 7;
        float acc = 0.0f;
        const float* wr = &fc2w[of * 32];
        #pragma unroll
        for (int m = 0; m < 4; ++m) {
            int j = l + 8 * m;
            acc += s_fch[j] * wr[j];
        }
        acc += __shfl_xor(acc, 1);
        acc += __shfl_xor(acc, 2);
        acc += __shfl_xor(acc, 4);
        if (l == 0) theta_ws[(size_t)n * 6 + of] = acc + fc2b[of];
    }
}

__launch_bounds__(256)
__global__ void stn_sample_kernel(
    const float* __restrict__ x,
    const float* __restrict__ theta_ws,
    float* __restrict__ out)
{
    const int t = threadIdx.x;
    const int n = blockIdx.x;
    const float* tw = theta_ws + (size_t)n * 6;
    const float t00 = tw[0], t01 = tw[1], t02 = tw[2];
    const float t10 = tw[3], t11 = tw[4], t12 = tw[5];
    const float* img = x + (size_t)n * 2352;       // HWC
    float* outp = out + (size_t)n * 2352;

    for (int p = t; p < 784; p += 256) {
        int h = p / 28, w = p - 28 * h;
        float xs = (2.0f * w + 1.0f) * (1.0f / 28.0f) - 1.0f;
        float ys = (2.0f * h + 1.0f) * (1.0f / 28.0f) - 1.0f;
        float gx = t00 * xs + t01 * ys + t02;
        float gy = t10 * xs + t11 * ys + t12;
        float ix = ((gx + 1.0f) * 28.0f - 1.0f) * 0.5f;
        float iy = ((gy + 1.0f) * 28.0f - 1.0f) * 0.5f;
        float x0f = floorf(ix), y0f = floorf(iy);
        float wx1 = ix - x0f, wx0 = 1.0f - wx1;
        float wy1 = iy - y0f, wy0 = 1.0f - wy1;
        int x0 = (int)x0f, y0 = (int)y0f;
        int x1 = x0 + 1, y1 = y0 + 1;
        float fx0 = (x0 >= 0 && x0 < 28) ? 1.0f : 0.0f;
        float fx1 = (x1 >= 0 && x1 < 28) ? 1.0f : 0.0f;
        float fy0 = (y0 >= 0 && y0 < 28) ? 1.0f : 0.0f;
        float fy1 = (y1 >= 0 && y1 < 28) ? 1.0f : 0.0f;
        float w00 = wx0 * wy0 * fx0 * fy0;
        float w10 = wx1 * wy0 * fx1 * fy0;
        float w01 = wx0 * wy1 * fx0 * fy1;
        float w11 = wx1 * wy1 * fx1 * fy1;
        int cx0 = min(max(x0, 0), 27), cx1 = min(max(x1, 0), 27);
        int cy0 = min(max(y0, 0), 27), cy1 = min(max(y1, 0), 27);
        const float* p00 = img + (cy0 * 28 + cx0) * 3;
        const float* p10 = img + (cy0 * 28 + cx1) * 3;
        const float* p01 = img + (cy1 * 28 + cx0) * 3;
        const float* p11 = img + (cy1 * 28 + cx1) * 3;
        float* o3 = outp + 3 * p;
        #pragma unroll
        for (int c = 0; c < 3; ++c) {
            o3[c] = p00[c] * w00 + p10[c] * w10 + p01[c] * w01 + p11[c] * w11;
        }
    }
}

extern "C" void kernel_launch(void* const* d_in, const int* in_sizes, int n_in,
                              void* d_out, int out_size, void* d_ws, size_t ws_size,
                              hipStream_t stream) {
    const float* x     = (const float*)d_in[0];
    const float* w1    = (const float*)d_in[1];
    const float* b1    = (const float*)d_in[2];
    const float* w2    = (const float*)d_in[3];
    const float* b2    = (const float*)d_in[4];
    const float* fc1w  = (const float*)d_in[5];
    const float* fc1b  = (const float*)d_in[6];
    const float* fc2w  = (const float*)d_in[7];
    const float* fc2b  = (const float*)d_in[8];
    float* outp  = (float*)d_out;
    float* theta = (float*)d_ws;   // 16384*6 floats = 393 KB

    const int n_img = 64 * 256;  // b*n
    stn_loc_kernel<<<dim3(n_img), dim3(256), 0, stream>>>(
        x, w1, b1, w2, b2, fc1w, fc1b, fc2w, fc2b, theta);
    stn_sample_kernel<<<dim3(n_img), dim3(256), 0, stream>>>(x, theta, outp);
}

// Round 7
// 339.973 us; speedup vs baseline: 1.4016x; 1.4016x over previous
//
#include <hip/hip_runtime.h>

// STN round 7: conv1 packed-fp32 via compiler (__builtin_elementwise_fma on
// float2 -> v_pk_fma_f32), NO inline asm (round 6's asm-pinned accumulators
// caused scratch spill: 313 MB WRITE). Row-pair accumulators keep maxpool
// in-register. Two 6-column halves per thread cap transient P at 12 v2f.
// Conv2 = round-4 60-thread form; fc1/fc2 widened; K2 sampling kernel as r5.

typedef float v2f __attribute__((ext_vector_type(2)));

__launch_bounds__(256, 4)
__global__ void stn_loc_kernel(
    const float* __restrict__ x,
    const float* __restrict__ w1, const float* __restrict__ b1,
    const float* __restrict__ w2, const float* __restrict__ b2,
    const float* __restrict__ fc1w, const float* __restrict__ fc1b,
    const float* __restrict__ fc2w, const float* __restrict__ fc2b,
    float* __restrict__ theta_ws)
{
    // image as row-pair layouts, float2-interleaved, row stride 30 pairs
    __shared__ __align__(16) float s2e_f[3 * 14 * 30 * 2];  // pairs (2a, 2a+1)
    __shared__ __align__(16) float s2o_f[3 * 13 * 30 * 2];  // pairs (2a+1, 2a+2)
    __shared__ __align__(16) float s_w1[8 * 3 * 7 * 7];     // 1176
    __shared__ __align__(16) float s_h1[8 * 11 * 12];       // pooled1, rows padded
    __shared__ float s_h2[90];
    __shared__ float s_fch[32];

    const int t = threadIdx.x;
    const int n = blockIdx.x;
    const float* img = x + (size_t)n * 2352;

    // ---- Stage A: image HWC -> phase-paired LDS CHW; w1 -> LDS
    for (int p = t; p < 784; p += 256) {
        const int h = p / 28, w = p - 28 * h;
        #pragma unroll
        for (int c = 0; c < 3; ++c) {
            const float v = img[3 * p + c];
            s2e_f[((c * 14 + (h >> 1)) * 30 + w) * 2 + (h & 1)] = v;
            if (h >= 1 && h <= 26) {
                s2o_f[((c * 13 + ((h - 1) >> 1)) * 30 + w) * 2 + ((h - 1) & 1)] = v;
            }
        }
    }
    for (int i = t; i < 1176; i += 256) s_w1[i] = w1[i];
    __syncthreads();

    // ---- Stage B: conv1 (3->8, 7x7) + 2x2 maxpool + relu -> s_h1 [8][11][12]
    // t = u*16 + o*2 + q: u = out-row-pair (0..10), o = channel, q = col half.
    // acc2[jj] = v2f{out[2u][col], out[2u+1][col]}, col = q*12 + jj.
    if (t < 176) {
        const int u = t >> 4;
        const int o = (t >> 1) & 7;
        const int q = t & 1;
        const int cb0 = q * 12;            // column base (v2f units)

        v2f acc2[12];
        const float bias = b1[o];
        #pragma unroll
        for (int j = 0; j < 12; ++j) acc2[j] = (v2f){bias, bias};

        for (int c = 0; c < 3; ++c) {
            #pragma unroll
            for (int kh = 0; kh < 7; ++kh) {
                const int a = u + (kh >> 1);
                const float* rowbase = (kh & 1)
                    ? &s2o_f[((c * 13 + a) * 30) * 2]
                    : &s2e_f[((c * 14 + a) * 30) * 2];
                // weights for this (o,c,kh), splat to both halves
                const float* wr = &s_w1[(o * 3 + c) * 49 + kh * 7];
                v2f wd[7];
                #pragma unroll
                for (int kw = 0; kw < 7; ++kw) {
                    const float wv = wr[kw];
                    wd[kw] = (v2f){wv, wv};
                }
                // two 6-column halves: P window 12 v2f each
                #pragma unroll
                for (int jh = 0; jh < 2; ++jh) {
                    const int cb = cb0 + jh * 6;
                    v2f P[12];
                    const float4* src = (const float4*)(rowbase + cb * 2);
                    #pragma unroll
                    for (int r = 0; r < 6; ++r) {
                        float4 v = src[r];
                        P[2 * r]     = (v2f){v.x, v.y};
                        P[2 * r + 1] = (v2f){v.z, v.w};
                    }
                    #pragma unroll
                    for (int kw = 0; kw < 7; ++kw) {
                        #pragma unroll
                        for (int j = 0; j < 6; ++j) {
                            acc2[jh * 6 + j] =
                                __builtin_elementwise_fma(P[j + kw], wd[kw],
                                                          acc2[jh * 6 + j]);
                        }
                    }
                }
            }
        }
        // maxpool fully in-register: rows are .x/.y, col pairs (2m, 2m+1)
        const int mmax = q ? 5 : 6;
        float* hrow = &s_h1[(o * 11 + u) * 12 + q * 6];
        #pragma unroll
        for (int m = 0; m < 6; ++m) {
            if (m < mmax) {
                float v = fmaxf(fmaxf(acc2[2 * m][0], acc2[2 * m][1]),
                                fmaxf(acc2[2 * m + 1][0], acc2[2 * m + 1][1]));
                hrow[m] = fmaxf(v, 0.0f);
            }
        }
    }
    __syncthreads();

    // ---- Stage D: conv2 (8->10, 5x5) + 2x2 maxpool + relu -> s_h2[90]
    // 60 threads (round-4 proven form); weights direct from global (L1/L2-hot).
    if (t < 60) {
        const int o = t / 6, i = t - 6 * (t / 6);
        float acc2[6];
        const float bias = b2[o];
        #pragma unroll
        for (int j = 0; j < 6; ++j) acc2[j] = bias;
        for (int c = 0; c < 8; ++c) {
            #pragma unroll
            for (int kh = 0; kh < 5; ++kh) {
                const float* hrow = &s_h1[(c * 11 + i + kh) * 12];
                float im2[12];
                #pragma unroll
                for (int qq = 0; qq < 3; ++qq) {
                    float4 v = ((const float4*)hrow)[qq];
                    im2[4 * qq + 0] = v.x; im2[4 * qq + 1] = v.y;
                    im2[4 * qq + 2] = v.z; im2[4 * qq + 3] = v.w;
                }
                const float* wr = &w2[(o * 8 + c) * 25 + kh * 5];
                float wv[5];
                #pragma unroll
                for (int qq = 0; qq < 5; ++qq) wv[qq] = wr[qq];
                #pragma unroll
                for (int kw = 0; kw < 5; ++kw) {
                    #pragma unroll
                    for (int j = 0; j < 6; ++j)
                        acc2[j] += im2[j + kw] * wv[kw];
                }
            }
        }
        float hp[3];
        #pragma unroll
        for (int qq = 0; qq < 3; ++qq) hp[qq] = fmaxf(acc2[2 * qq], acc2[2 * qq + 1]);
        #pragma unroll
        for (int qq = 0; qq < 3; ++qq) {
            float v = __shfl_xor(hp[qq], 1);   // partner i^1 = lane^1
            hp[qq] = fmaxf(hp[qq], v);
        }
        if ((i & 1) == 0) {
            #pragma unroll
            for (int qq = 0; qq < 3; ++qq)
                s_h2[o * 9 + (i >> 1) * 3 + qq] = fmaxf(hp[qq], 0.0f);
        }
    }
    __syncthreads();

    // ---- Stage F: fc1 (90->32) + relu; 256 threads = 32 outputs x 8 lanes
    {
        const int of = t >> 3, l = t & 7;
        float acc = 0.0f;
        const float* wr = &fc1w[of * 90];
        #pragma unroll
        for (int m = 0; m < 12; ++m) {
            int j = l + 8 * m;
            if (j < 90) acc += s_h2[j] * wr[j];
        }
        acc += __shfl_xor(acc, 1);
        acc += __shfl_xor(acc, 2);
        acc += __shfl_xor(acc, 4);
        if (l == 0) s_fch[of] = fmaxf(acc + fc1b[of], 0.0f);
    }
    __syncthreads();

    // ---- Stage G: fc2 (32->6); 48 threads = 6 outputs x 8 lanes -> theta
    if (t < 48) {
        const int of = t >> 3, l = t & 7;
        float acc = 0.0f;
        const float* wr = &fc2w[of * 32];
        #pragma unroll
        for (int m = 0; m < 4; ++m) {
            int j = l + 8 * m;
            acc += s_fch[j] * wr[j];
        }
        acc += __shfl_xor(acc, 1);
        acc += __shfl_xor(acc, 2);
        acc += __shfl_xor(acc, 4);
        if (l == 0) theta_ws[(size_t)n * 6 + of] = acc + fc2b[of];
    }
}

__launch_bounds__(256)
__global__ void stn_sample_kernel(
    const float* __restrict__ x,
    const float* __restrict__ theta_ws,
    float* __restrict__ out)
{
    const int t = threadIdx.x;
    const int n = blockIdx.x;
    const float* tw = theta_ws + (size_t)n * 6;
    const float t00 = tw[0], t01 = tw[1], t02 = tw[2];
    const float t10 = tw[3], t11 = tw[4], t12 = tw[5];
    const float* img = x + (size_t)n * 2352;       // HWC
    float* outp = out + (size_t)n * 2352;

    for (int p = t; p < 784; p += 256) {
        int h = p / 28, w = p - 28 * h;
        float xs = (2.0f * w + 1.0f) * (1.0f / 28.0f) - 1.0f;
        float ys = (2.0f * h + 1.0f) * (1.0f / 28.0f) - 1.0f;
        float gx = t00 * xs + t01 * ys + t02;
        float gy = t10 * xs + t11 * ys + t12;
        float ix = ((gx + 1.0f) * 28.0f - 1.0f) * 0.5f;
        float iy = ((gy + 1.0f) * 28.0f - 1.0f) * 0.5f;
        float x0f = floorf(ix), y0f = floorf(iy);
        float wx1 = ix - x0f, wx0 = 1.0f - wx1;
        float wy1 = iy - y0f, wy0 = 1.0f - wy1;
        int x0 = (int)x0f, y0 = (int)y0f;
        int x1 = x0 + 1, y1 = y0 + 1;
        float fx0 = (x0 >= 0 && x0 < 28) ? 1.0f : 0.0f;
        float fx1 = (x1 >= 0 && x1 < 28) ? 1.0f : 0.0f;
        float fy0 = (y0 >= 0 && y0 < 28) ? 1.0f : 0.0f;
        float fy1 = (y1 >= 0 && y1 < 28) ? 1.0f : 0.0f;
        float w00 = wx0 * wy0 * fx0 * fy0;
        float w10 = wx1 * wy0 * fx1 * fy0;
        float w01 = wx0 * wy1 * fx0 * fy1;
        float w11 = wx1 * wy1 * fx1 * fy1;
        int cx0 = min(max(x0, 0), 27), cx1 = min(max(x1, 0), 27);
        int cy0 = min(max(y0, 0), 27), cy1 = min(max(y1, 0), 27);
        const float* p00 = img + (cy0 * 28 + cx0) * 3;
        const float* p10 = img + (cy0 * 28 + cx1) * 3;
        const float* p01 = img + (cy1 * 28 + cx0) * 3;
        const float* p11 = img + (cy1 * 28 + cx1) * 3;
        float* o3 = outp + 3 * p;
        #pragma unroll
        for (int c = 0; c < 3; ++c) {
            o3[c] = p00[c] * w00 + p10[c] * w10 + p01[c] * w01 + p11[c] * w11;
        }
    }
}

extern "C" void kernel_launch(void* const* d_in, const int* in_sizes, int n_in,
                              void* d_out, int out_size, void* d_ws, size_t ws_size,
                              hipStream_t stream) {
    const float* x     = (const float*)d_in[0];
    const float* w1    = (const float*)d_in[1];
    const float* b1    = (const float*)d_in[2];
    const float* w2    = (const float*)d_in[3];
    const float* b2    = (const float*)d_in[4];
    const float* fc1w  = (const float*)d_in[5];
    const float* fc1b  = (const float*)d_in[6];
    const float* fc2w  = (const float*)d_in[7];
    const float* fc2b  = (const float*)d_in[8];
    float* outp  = (float*)d_out;
    float* theta = (float*)d_ws;   // 16384*6 floats = 393 KB

    const int n_img = 64 * 256;  // b*n
    stn_loc_kernel<<<dim3(n_img), dim3(256), 0, stream>>>(
        x, w1, b1, w2, b2, fc1w, fc1b, fc2w, fc2b, theta);
    stn_sample_kernel<<<dim3(n_img), dim3(256), 0, stream>>>(x, theta, outp);
}

// Round 8
// 313.207 us; speedup vs baseline: 1.5214x; 1.0855x over previous
//
#include <hip/hip_runtime.h>

// STN round 8: conv1 via v_dot2_f32_f16 (fdot2) — 2 MAC/inst, fp32 accumulate.
// Image f16 in LDS [3][28][40] (80B row stride: conflict-free + 16B aligned,
// cols 28..39 zeroed). Weights prepacked as half2 kw-pairs. Thread map, pooling,
// conv2, fc1/fc2, K2 all keep their proven round-2/5/7 forms.

typedef _Float16 half2_t __attribute__((ext_vector_type(2)));

static __device__ inline half2_t h2(uint32_t u) {
    union { uint32_t u; half2_t h; } cv; cv.u = u; return cv.h;
}

#if __has_builtin(__builtin_amdgcn_fdot2)
#define FDOT2(a, b, c) __builtin_amdgcn_fdot2((a), (b), (c), false)
#else
#define FDOT2(a, b, c) ((float)(a)[0] * (float)(b)[0] + (float)(a)[1] * (float)(b)[1] + (c))
#endif

__launch_bounds__(256, 4)
__global__ void stn_loc_kernel(
    const float* __restrict__ x,
    const float* __restrict__ w1, const float* __restrict__ b1,
    const float* __restrict__ w2, const float* __restrict__ b2,
    const float* __restrict__ fc1w, const float* __restrict__ fc1b,
    const float* __restrict__ fc2w, const float* __restrict__ fc2b,
    float* __restrict__ theta_ws)
{
    __shared__ __align__(16) _Float16 s_imgh[3 * 28 * 40];  // 6720 B, CHW f16, padded cols
    __shared__ __align__(16) uint32_t s_w1p[8 * 21 * 4];    // 2688 B, half2 kw-pairs
    __shared__ __align__(16) float s_h1[8 * 11 * 12];       // pooled1 fp32, rows padded
    __shared__ float s_h2[90];
    __shared__ float s_fch[32];

    const int t = threadIdx.x;
    const int n = blockIdx.x;
    const float* img = x + (size_t)n * 2352;

    // ---- Stage A: zero pad region (disjoint from data writes, same pass)
    for (int idx = t; idx < 504; idx += 256) {
        const int cc = idx / 168;
        const int rem = idx - 168 * cc;
        const int hh = rem / 6;
        const int kk = rem - 6 * hh;
        ((uint32_t*)s_imgh)[(((cc * 28 + hh) * 40) + 28 + 2 * kk) >> 1] = 0u;
    }
    // image HWC fp32 -> LDS CHW f16
    for (int p = t; p < 784; p += 256) {
        const int h = p / 28, w = p - 28 * h;
        const float v0 = img[3 * p + 0];
        const float v1 = img[3 * p + 1];
        const float v2 = img[3 * p + 2];
        s_imgh[(0 * 28 + h) * 40 + w] = (_Float16)v0;
        s_imgh[(1 * 28 + h) * 40 + w] = (_Float16)v1;
        s_imgh[(2 * 28 + h) * 40 + w] = (_Float16)v2;
    }
    // w1 -> half2 kw-pairs: idx = (o*21 + c*7 + kh)*4 + p, pair = {w[2p], w[2p+1]|0}
    for (int idx = t; idx < 672; idx += 256) {
        const int o = idx / 84;  const int rem = idx - 84 * o;
        const int c = rem / 28;  const int r2 = rem - 28 * c;
        const int kh = r2 >> 2;  const int p = r2 & 3;
        const int k0 = 2 * p;
        const float* wbase = &w1[((o * 3 + c) * 7 + kh) * 7];
        const float wa = wbase[k0];
        const float wb = (k0 + 1 < 7) ? wbase[k0 + 1] : 0.0f;
        union { half2_t h; uint32_t u; } cv;
        cv.h = (half2_t){(_Float16)wa, (_Float16)wb};
        s_w1p[idx] = cv.u;
    }
    __syncthreads();

    // ---- Stage B: conv1 (3->8, 7x7) + 2x2 maxpool + relu -> s_h1 [8][11][12]
    // t = i*8 + o (proven map): wave = 8 distinct rows x 8 broadcast channels.
    if (t < 176) {
        const int i = t >> 3, o = t & 7;
        float acc[22];
        const float bias = b1[o];
        #pragma unroll
        for (int j = 0; j < 22; ++j) acc[j] = bias;

        for (int c = 0; c < 3; ++c) {
            #pragma unroll
            for (int kh = 0; kh < 7; ++kh) {
                const uint32_t* rowu =
                    (const uint32_t*)&s_imgh[(c * 28 + i + kh) * 40];
                uint32_t E[16];
                {
                    const uint4 a = ((const uint4*)rowu)[0];
                    const uint4 b = ((const uint4*)rowu)[1];
                    const uint4 cq = ((const uint4*)rowu)[2];
                    const uint4 d = ((const uint4*)rowu)[3];
                    E[0] = a.x;  E[1] = a.y;  E[2] = a.z;  E[3] = a.w;
                    E[4] = b.x;  E[5] = b.y;  E[6] = b.z;  E[7] = b.w;
                    E[8] = cq.x; E[9] = cq.y; E[10] = cq.z; E[11] = cq.w;
                    E[12] = d.x; E[13] = d.y; E[14] = d.z; E[15] = d.w;
                }
                uint32_t O[14];
                #pragma unroll
                for (int k = 0; k < 14; ++k)
                    O[k] = (E[k] >> 16) | (E[k + 1] << 16);   // halves (2k+1, 2k+2)

                const uint4 wq = *(const uint4*)&s_w1p[(o * 21 + c * 7 + kh) * 4];
                const half2_t wp0 = h2(wq.x), wp1 = h2(wq.y);
                const half2_t wp2 = h2(wq.z), wp3 = h2(wq.w);

                #pragma unroll
                for (int j = 0; j < 22; j += 2) {
                    const int b0 = j >> 1;
                    acc[j]     = FDOT2(h2(E[b0]),     wp0, acc[j]);
                    acc[j]     = FDOT2(h2(E[b0 + 1]), wp1, acc[j]);
                    acc[j]     = FDOT2(h2(E[b0 + 2]), wp2, acc[j]);
                    acc[j]     = FDOT2(h2(E[b0 + 3]), wp3, acc[j]);
                    acc[j + 1] = FDOT2(h2(O[b0]),     wp0, acc[j + 1]);
                    acc[j + 1] = FDOT2(h2(O[b0 + 1]), wp1, acc[j + 1]);
                    acc[j + 1] = FDOT2(h2(O[b0 + 2]), wp2, acc[j + 1]);
                    acc[j + 1] = FDOT2(h2(O[b0 + 3]), wp3, acc[j + 1]);
                }
            }
        }
        // horizontal pair-max in regs
        float hm[11];
        #pragma unroll
        for (int j = 0; j < 11; ++j) hm[j] = fmaxf(acc[2 * j], acc[2 * j + 1]);
        // vertical pair-max via shfl: partner row i^1 = lane^8
        #pragma unroll
        for (int j = 0; j < 11; ++j) {
            float v = __shfl_xor(hm[j], 8);
            hm[j] = fmaxf(hm[j], v);
        }
        if ((i & 1) == 0) {
            float* row = &s_h1[(o * 11 + (i >> 1)) * 12];
            #pragma unroll
            for (int j = 0; j < 11; ++j) row[j] = fmaxf(hm[j], 0.0f);
        }
    }
    __syncthreads();

    // ---- Stage D: conv2 (8->10, 5x5) + 2x2 maxpool + relu -> s_h2[90]
    // 60 threads (proven form); weights direct from global (L1/L2-hot).
    if (t < 60) {
        const int o = t / 6, i = t - 6 * (t / 6);
        float acc2[6];
        const float bias = b2[o];
        #pragma unroll
        for (int j = 0; j < 6; ++j) acc2[j] = bias;
        for (int c = 0; c < 8; ++c) {
            #pragma unroll
            for (int kh = 0; kh < 5; ++kh) {
                const float* hrow = &s_h1[(c * 11 + i + kh) * 12];
                float im2[12];
                #pragma unroll
                for (int qq = 0; qq < 3; ++qq) {
                    float4 v = ((const float4*)hrow)[qq];
                    im2[4 * qq + 0] = v.x; im2[4 * qq + 1] = v.y;
                    im2[4 * qq + 2] = v.z; im2[4 * qq + 3] = v.w;
                }
                const float* wr = &w2[(o * 8 + c) * 25 + kh * 5];
                float wv[5];
                #pragma unroll
                for (int qq = 0; qq < 5; ++qq) wv[qq] = wr[qq];
                #pragma unroll
                for (int kw = 0; kw < 5; ++kw) {
                    #pragma unroll
                    for (int j = 0; j < 6; ++j)
                        acc2[j] += im2[j + kw] * wv[kw];
                }
            }
        }
        float hp[3];
        #pragma unroll
        for (int qq = 0; qq < 3; ++qq) hp[qq] = fmaxf(acc2[2 * qq], acc2[2 * qq + 1]);
        #pragma unroll
        for (int qq = 0; qq < 3; ++qq) {
            float v = __shfl_xor(hp[qq], 1);   // partner i^1 = lane^1
            hp[qq] = fmaxf(hp[qq], v);
        }
        if ((i & 1) == 0) {
            #pragma unroll
            for (int qq = 0; qq < 3; ++qq)
                s_h2[o * 9 + (i >> 1) * 3 + qq] = fmaxf(hp[qq], 0.0f);
        }
    }
    __syncthreads();

    // ---- Stage F: fc1 (90->32) + relu; 256 threads = 32 outputs x 8 lanes
    {
        const int of = t >> 3, l = t & 7;
        float acc = 0.0f;
        const float* wr = &fc1w[of * 90];
        #pragma unroll
        for (int m = 0; m < 12; ++m) {
            int j = l + 8 * m;
            if (j < 90) acc += s_h2[j] * wr[j];
        }
        acc += __shfl_xor(acc, 1);
        acc += __shfl_xor(acc, 2);
        acc += __shfl_xor(acc, 4);
        if (l == 0) s_fch[of] = fmaxf(acc + fc1b[of], 0.0f);
    }
    __syncthreads();

    // ---- Stage G: fc2 (32->6); 48 threads = 6 outputs x 8 lanes -> theta
    if (t < 48) {
        const int of = t >> 3, l = t & 7;
        float acc = 0.0f;
        const float* wr = &fc2w[of * 32];
        #pragma unroll
        for (int m = 0; m < 4; ++m) {
            int j = l + 8 * m;
            acc += s_fch[j] * wr[j];
        }
        acc += __shfl_xor(acc, 1);
        acc += __shfl_xor(acc, 2);
        acc += __shfl_xor(acc, 4);
        if (l == 0) theta_ws[(size_t)n * 6 + of] = acc + fc2b[of];
    }
}

__launch_bounds__(256)
__global__ void stn_sample_kernel(
    const float* __restrict__ x,
    const float* __restrict__ theta_ws,
    float* __restrict__ out)
{
    const int t = threadIdx.x;
    const int n = blockIdx.x;
    const float* tw = theta_ws + (size_t)n * 6;
    const float t00 = tw[0], t01 = tw[1], t02 = tw[2];
    const float t10 = tw[3], t11 = tw[4], t12 = tw[5];
    const float* img = x + (size_t)n * 2352;       // HWC
    float* outp = out + (size_t)n * 2352;

    for (int p = t; p < 784; p += 256) {
        int h = p / 28, w = p - 28 * h;
        float xs = (2.0f * w + 1.0f) * (1.0f / 28.0f) - 1.0f;
        float ys = (2.0f * h + 1.0f) * (1.0f / 28.0f) - 1.0f;
        float gx = t00 * xs + t01 * ys + t02;
        float gy = t10 * xs + t11 * ys + t12;
        float ix = ((gx + 1.0f) * 28.0f - 1.0f) * 0.5f;
        float iy = ((gy + 1.0f) * 28.0f - 1.0f) * 0.5f;
        float x0f = floorf(ix), y0f = floorf(iy);
        float wx1 = ix - x0f, wx0 = 1.0f - wx1;
        float wy1 = iy - y0f, wy0 = 1.0f - wy1;
        int x0 = (int)x0f, y0 = (int)y0f;
        int x1 = x0 + 1, y1 = y0 + 1;
        float fx0 = (x0 >= 0 && x0 < 28) ? 1.0f : 0.0f;
        float fx1 = (x1 >= 0 && x1 < 28) ? 1.0f : 0.0f;
        float fy0 = (y0 >= 0 && y0 < 28) ? 1.0f : 0.0f;
        float fy1 = (y1 >= 0 && y1 < 28) ? 1.0f : 0.0f;
        float w00 = wx0 * wy0 * fx0 * fy0;
        float w10 = wx1 * wy0 * fx1 * fy0;
        float w01 = wx0 * wy1 * fx0 * fy1;
        float w11 = wx1 * wy1 * fx1 * fy1;
        int cx0 = min(max(x0, 0), 27), cx1 = min(max(x1, 0), 27);
        int cy0 = min(max(y0, 0), 27), cy1 = min(max(y1, 0), 27);
        const float* p00 = img + (cy0 * 28 + cx0) * 3;
        const float* p10 = img + (cy0 * 28 + cx1) * 3;
        const float* p01 = img + (cy1 * 28 + cx0) * 3;
        const float* p11 = img + (cy1 * 28 + cx1) * 3;
        float* o3 = outp + 3 * p;
        #pragma unroll
        for (int c = 0; c < 3; ++c) {
            o3[c] = p00[c] * w00 + p10[c] * w10 + p01[c] * w01 + p11[c] * w11;
        }
    }
}

extern "C" void kernel_launch(void* const* d_in, const int* in_sizes, int n_in,
                              void* d_out, int out_size, void* d_ws, size_t ws_size,
                              hipStream_t stream) {
    const float* x     = (const float*)d_in[0];
    const float* w1    = (const float*)d_in[1];
    const float* b1    = (const float*)d_in[2];
    const float* w2    = (const float*)d_in[3];
    const float* b2    = (const float*)d_in[4];
    const float* fc1w  = (const float*)d_in[5];
    const float* fc1b  = (const float*)d_in[6];
    const float* fc2w  = (const float*)d_in[7];
    const float* fc2b  = (const float*)d_in[8];
    float* outp  = (float*)d_out;
    float* theta = (float*)d_ws;   // 16384*6 floats = 393 KB

    const int n_img = 64 * 256;  // b*n
    stn_loc_kernel<<<dim3(n_img), dim3(256), 0, stream>>>(
        x, w1, b1, w2, b2, fc1w, fc1b, fc2w, fc2b, theta);
    stn_sample_kernel<<<dim3(n_img), dim3(256), 0, stream>>>(x, theta, outp);
}